// Round 1
// baseline (443.059 us; speedup 1.0000x reference)
//
#include <hip/hip_runtime.h>

#define SEQ 2048
#define BATCH 32
#define HID 1024

// Kernel 1: v[b,h] = sum_k hidden[b,k] * W[k,h]   (v = hidden @ W)
// One block per b; hidden row staged in LDS; thread t owns float4 at h=[4t..4t+3].
__global__ void __launch_bounds__(256) vproj_kernel(const float* __restrict__ hidden,
                                                    const float* __restrict__ W,
                                                    float* __restrict__ v) {
    const int b = blockIdx.x;
    const int t = threadIdx.x;
    __shared__ float sh[HID];
    for (int i = t; i < HID; i += 256) sh[i] = hidden[b * HID + i];
    __syncthreads();

    const float4* __restrict__ W4 = (const float4*)W;  // [HID][HID/4]
    float4 acc = make_float4(0.f, 0.f, 0.f, 0.f);
#pragma unroll 8
    for (int k = 0; k < HID; ++k) {
        const float hk = sh[k];                 // LDS broadcast, conflict-free
        const float4 w = W4[k * (HID / 4) + t]; // coalesced 16B/lane
        acc.x = fmaf(hk, w.x, acc.x);
        acc.y = fmaf(hk, w.y, acc.y);
        acc.z = fmaf(hk, w.z, acc.z);
        acc.w = fmaf(hk, w.w, acc.w);
    }
    ((float4*)v)[b * (HID / 4) + t] = acc;
}

// Kernel 2: scores[b,s] = enc[s,b,:] . v[b,:]
// One wave per (s,b). Block = 4 waves = 4 consecutive b at the same s
// (contiguous 16 KB of enc per block). enc read exactly once -> HBM floor.
__global__ void __launch_bounds__(256) score_kernel(const float* __restrict__ enc,
                                                    const float* __restrict__ v,
                                                    float* __restrict__ scores) {
    const int s = blockIdx.x;
    const int wave = threadIdx.x >> 6;
    const int lane = threadIdx.x & 63;
    const int b = blockIdx.y * 4 + wave;

    const float4* __restrict__ e4 = (const float4*)(enc + ((size_t)s * BATCH + b) * HID);
    const float4* __restrict__ v4 = (const float4*)(v + b * HID);

    float acc = 0.f;
#pragma unroll
    for (int j = 0; j < 4; ++j) {
        const float4 e = e4[j * 64 + lane];  // coalesced 16B/lane
        const float4 w = v4[j * 64 + lane];  // 4KB working set/b -> cache-resident
        acc = fmaf(e.x, w.x, acc);
        acc = fmaf(e.y, w.y, acc);
        acc = fmaf(e.z, w.z, acc);
        acc = fmaf(e.w, w.w, acc);
    }
#pragma unroll
    for (int off = 32; off > 0; off >>= 1) acc += __shfl_xor(acc, off, 64);
    if (lane == 0) scores[b * SEQ + s] = acc;
}

// Kernel 3: out[b,s] = softmax_s(scores[b,:]). One block per b.
__global__ void __launch_bounds__(256) softmax_kernel(const float* __restrict__ scores,
                                                      float* __restrict__ out) {
    const int b = blockIdx.x;
    const int t = threadIdx.x;
    __shared__ float red[256];

    float x[8];
    float m = -INFINITY;
#pragma unroll
    for (int j = 0; j < 8; ++j) {
        x[j] = scores[b * SEQ + t + j * 256];
        m = fmaxf(m, x[j]);
    }
    red[t] = m;
    __syncthreads();
    for (int o = 128; o > 0; o >>= 1) {
        if (t < o) red[t] = fmaxf(red[t], red[t + o]);
        __syncthreads();
    }
    m = red[0];
    __syncthreads();

    float sum = 0.f;
#pragma unroll
    for (int j = 0; j < 8; ++j) {
        x[j] = __expf(x[j] - m);
        sum += x[j];
    }
    red[t] = sum;
    __syncthreads();
    for (int o = 128; o > 0; o >>= 1) {
        if (t < o) red[t] += red[t + o];
        __syncthreads();
    }
    const float inv = 1.f / red[0];
#pragma unroll
    for (int j = 0; j < 8; ++j) out[b * SEQ + t + j * 256] = x[j] * inv;
}

extern "C" void kernel_launch(void* const* d_in, const int* in_sizes, int n_in,
                              void* d_out, int out_size, void* d_ws, size_t ws_size,
                              hipStream_t stream) {
    const float* hidden = (const float*)d_in[0];  // [B,H]
    const float* enc    = (const float*)d_in[1];  // [S,B,H]
    const float* W      = (const float*)d_in[2];  // [H,H]
    // d_in[3] = bias: constant over s per b -> cancels in softmax; unused.
    float* out = (float*)d_out;                   // [1,B,S] fp32

    float* v      = (float*)d_ws;                 // B*H   floats (128 KB)
    float* scores = v + BATCH * HID;              // B*S   floats (256 KB)

    vproj_kernel<<<BATCH, 256, 0, stream>>>(hidden, W, v);
    score_kernel<<<dim3(SEQ, BATCH / 4), 256, 0, stream>>>(enc, v, scores);
    softmax_kernel<<<BATCH, 256, 0, stream>>>(scores, out);
}

// Round 2
// 377.856 us; speedup vs baseline: 1.1726x; 1.1726x over previous
//
#include <hip/hip_runtime.h>

#define SEQ 2048
#define BATCH 32
#define HID 1024

// Kernel 1: v[b,h] = sum_k hidden[b,k] * W[k,h]   (v = hidden @ W)
// Split-K: grid (b, hc) = (32, 8) = 256 blocks (one per CU).
// Block (b,hc) owns h4 columns [hc*32, hc*32+32) (float4 units = 128 floats).
// Thread t: h4 = hc*32 + (t&31), K-strip kk = t>>5 (8 strips x 128 k).
// LDS tree-reduce over the 8 K-strips at the end.
__global__ void __launch_bounds__(256) vproj_kernel(const float* __restrict__ hidden,
                                                    const float* __restrict__ W,
                                                    float* __restrict__ v) {
    const int b  = blockIdx.x;
    const int hc = blockIdx.y;
    const int t  = threadIdx.x;
    const int h4 = hc * 32 + (t & 31);
    const int kk = t >> 5;

    __shared__ float  sh[HID];
    __shared__ float4 red[256];

    // stage hidden row
    ((float4*)sh)[t] = ((const float4*)(hidden + b * HID))[t];
    __syncthreads();

    const float4* __restrict__ W4 = (const float4*)W;  // [HID][HID/4]
    float4 acc = make_float4(0.f, 0.f, 0.f, 0.f);
    const int k0 = kk * 128;
#pragma unroll 8
    for (int k = k0; k < k0 + 128; ++k) {
        const float  hk = sh[k];
        const float4 w  = W4[k * (HID / 4) + h4];  // 512B contiguous per 32 lanes
        acc.x = fmaf(hk, w.x, acc.x);
        acc.y = fmaf(hk, w.y, acc.y);
        acc.z = fmaf(hk, w.z, acc.z);
        acc.w = fmaf(hk, w.w, acc.w);
    }

    // reduce over kk (stride 32 in red[])
    red[t] = acc;
    __syncthreads();
    if (t < 128) {
        float4 a = red[t], c = red[t + 128];
        a.x += c.x; a.y += c.y; a.z += c.z; a.w += c.w;
        red[t] = a;
    }
    __syncthreads();
    if (t < 64) {
        float4 a = red[t], c = red[t + 64];
        a.x += c.x; a.y += c.y; a.z += c.z; a.w += c.w;
        red[t] = a;
    }
    __syncthreads();
    if (t < 32) {
        float4 a = red[t], c = red[t + 32];
        a.x += c.x; a.y += c.y; a.z += c.z; a.w += c.w;
        ((float4*)v)[b * (HID / 4) + hc * 32 + t] = a;
    }
}

// Kernel 2: scores[b,s] = enc[s,b,:] . v[b,:]
// One wave per (s,b). Block = 4 waves = 4 consecutive b at the same s
// (contiguous 16 KB of enc per block). enc read exactly once -> HBM floor.
__global__ void __launch_bounds__(256) score_kernel(const float* __restrict__ enc,
                                                    const float* __restrict__ v,
                                                    float* __restrict__ scores) {
    const int s = blockIdx.x;
    const int wave = threadIdx.x >> 6;
    const int lane = threadIdx.x & 63;
    const int b = blockIdx.y * 4 + wave;

    const float4* __restrict__ e4 = (const float4*)(enc + ((size_t)s * BATCH + b) * HID);
    const float4* __restrict__ v4 = (const float4*)(v + b * HID);

    float acc = 0.f;
#pragma unroll
    for (int j = 0; j < 4; ++j) {
        const float4 e = e4[j * 64 + lane];  // coalesced 16B/lane
        const float4 w = v4[j * 64 + lane];  // 4KB working set/b -> cache-resident
        acc = fmaf(e.x, w.x, acc);
        acc = fmaf(e.y, w.y, acc);
        acc = fmaf(e.z, w.z, acc);
        acc = fmaf(e.w, w.w, acc);
    }
#pragma unroll
    for (int off = 32; off > 0; off >>= 1) acc += __shfl_xor(acc, off, 64);
    if (lane == 0) scores[b * SEQ + s] = acc;
}

// Kernel 3: out[b,s] = softmax_s(scores[b,:]). One block per b.
__global__ void __launch_bounds__(256) softmax_kernel(const float* __restrict__ scores,
                                                      float* __restrict__ out) {
    const int b = blockIdx.x;
    const int t = threadIdx.x;
    __shared__ float red[256];

    float x[8];
    float m = -INFINITY;
#pragma unroll
    for (int j = 0; j < 8; ++j) {
        x[j] = scores[b * SEQ + t + j * 256];
        m = fmaxf(m, x[j]);
    }
    red[t] = m;
    __syncthreads();
    for (int o = 128; o > 0; o >>= 1) {
        if (t < o) red[t] = fmaxf(red[t], red[t + o]);
        __syncthreads();
    }
    m = red[0];
    __syncthreads();

    float sum = 0.f;
#pragma unroll
    for (int j = 0; j < 8; ++j) {
        x[j] = __expf(x[j] - m);
        sum += x[j];
    }
    red[t] = sum;
    __syncthreads();
    for (int o = 128; o > 0; o >>= 1) {
        if (t < o) red[t] += red[t + o];
        __syncthreads();
    }
    const float inv = 1.f / red[0];
#pragma unroll
    for (int j = 0; j < 8; ++j) out[b * SEQ + t + j * 256] = x[j] * inv;
}

extern "C" void kernel_launch(void* const* d_in, const int* in_sizes, int n_in,
                              void* d_out, int out_size, void* d_ws, size_t ws_size,
                              hipStream_t stream) {
    const float* hidden = (const float*)d_in[0];  // [B,H]
    const float* enc    = (const float*)d_in[1];  // [S,B,H]
    const float* W      = (const float*)d_in[2];  // [H,H]
    // d_in[3] = bias: constant over s per b -> cancels in softmax; unused.
    float* out = (float*)d_out;                   // [1,B,S] fp32

    float* v      = (float*)d_ws;                 // B*H   floats (128 KB)
    float* scores = v + BATCH * HID;              // B*S   floats (256 KB)

    vproj_kernel<<<dim3(BATCH, 8), 256, 0, stream>>>(hidden, W, v);
    score_kernel<<<dim3(SEQ, BATCH / 4), 256, 0, stream>>>(enc, v, scores);
    softmax_kernel<<<BATCH, 256, 0, stream>>>(scores, out);
}